// Round 12
// baseline (36.631 us; speedup 1.0000x reference)
//
#include <hip/hip_runtime.h>
#include <math.h>

#define NCOL 8192
#define BT   512
#define EPT  16
#define ROWS 8
#define NF4  2048   // float4 per row

// exact double constants
#define MZM_LOSS_D 0.8912509381337456   // 10^-0.05
#define YB_LOSS_D  0.9332543007969910   // 10^-0.03
#define MRR_LOSS_D 0.8912509381337456   // 10^-0.05

typedef __attribute__((address_space(3))) void       lds_void_t;
typedef const __attribute__((address_space(1))) void g_void_t;

static __device__ __forceinline__ void lds_barrier() {
    // drain LDS/SMEM only; global_load_lds prefetch stays in flight
    asm volatile("s_waitcnt lgkmcnt(0)" ::: "memory");
    __builtin_amdgcn_s_barrier();
}

// float4-level XOR swizzle (involution): spreads 64B-window reads across banks
static __device__ __forceinline__ int swz(int g) { return g ^ ((g >> 3) & 7); }

// Markstein: dst = rint(f32div(a, inorm) * 255), exact IEEE f32 division
#define QF(dst, a_) do {                                   \
    const float a__  = (a_);                               \
    const float q0__ = a__ * y;                            \
    const float r__  = fmaf(-inorm, q0__, a__);            \
    (dst) = rintf(fmaf(r__, y, q0__) * 255.f);             \
} while (0)

__global__ __launch_bounds__(BT, 4)
void odp_main(const float* __restrict__ x, const float* __restrict__ w,
              const float* __restrict__ ntp, const float* __restrict__ nsp,
              const float* __restrict__ ntn, const float* __restrict__ nsn,
              float* __restrict__ out)
{
    __shared__ float4 xs[2][NF4];     // 64 KB double buffer
    __shared__ float  redX[8], redW[8], redT[8];
    __shared__ double redD[8];
    __shared__ double corrd[4];       // cD(t0), cT(t0), cD(tLast), cT(tLast)

    const int t    = threadIdx.x;
    const int lane = t & 63;
    const int wid  = t >> 6;
    const int r0   = blockIdx.x * ROWS;

    const double DE0 = -((double)0.01f + (double)0.0025f);  // elems 0, N-1
    const double DE1 = -((double)0.0025f);                  // elems 1, N-2
    const double E_MID = 1.0 + 2.0 * (double)0.01f + 2.0 * (double)0.0025f;

    // ---- prologue: w -> regs (+ wave max|w|), stage row 0 into buf 0 ----
    const float4* __restrict__ w4 = (const float4*)w;
    float wf[EPT];
    float mw = 0.f;
#pragma unroll
    for (int j = 0; j < 4; ++j) {
        const float4 wv = w4[t * 4 + j];
        wf[4*j+0]=wv.x; wf[4*j+1]=wv.y; wf[4*j+2]=wv.z; wf[4*j+3]=wv.w;
        mw = fmaxf(mw, fmaxf(fmaxf(fabsf(wv.x), fabsf(wv.y)),
                             fmaxf(fabsf(wv.z), fabsf(wv.w))));
    }

#define STAGE(BUF, ROW) do {                                                  \
    const float* xr_ = x + (size_t)(ROW) * NCOL;                              \
    _Pragma("unroll")                                                         \
    for (int k = 0; k < 4; ++k) {                                             \
        const int phys_ = ((wid * 4 + k) << 6) | lane;                        \
        __builtin_amdgcn_global_load_lds(                                     \
            (g_void_t*)(xr_ + 4 * swz(phys_)),                                \
            (lds_void_t*)&xs[BUF][(wid * 4 + k) << 6], 16, 0, 0);             \
    }                                                                         \
} while (0)

    STAGE(0, r0);

    // precomputed swizzled read indices (same for both buffers)
    int wi[4];
#pragma unroll
    for (int k = 0; k < 4; ++k) wi[k] = swz(4 * t + k);
    const int hiL = swz((t > 0)      ? (4 * t - 1) : 0);        // dwords 16t-2,-1 in .z,.w
    const int hiR = swz((t < BT - 1) ? (4 * t + 4) : (NF4 - 1));// dwords 16t+16,+17 in .x,.y

    float wnorm = 1.f;     // valid in thread 0 after row 0
    float ov[ROWS];        // per-row outputs, thread 0 only

#pragma unroll
    for (int r = 0; r < ROWS; ++r) {
        const int buf = r & 1;
        if (r < ROWS - 1) {
            STAGE(buf ^ 1, r0 + r + 1);
            asm volatile("s_waitcnt vmcnt(4)" ::: "memory");  // row r staged; r+1 in flight
        } else {
            asm volatile("s_waitcnt vmcnt(0)" ::: "memory");
        }

        // ---- own 16 elems from LDS (conflict-free swizzled b128) ----
        float xf[EPT];
#pragma unroll
        for (int k = 0; k < 4; ++k) {
            const float4 v = xs[buf][wi[k]];
            xf[4*k+0]=v.x; xf[4*k+1]=v.y; xf[4*k+2]=v.z; xf[4*k+3]=v.w;
        }
        float mx = 0.f;
#pragma unroll
        for (int c = 0; c < EPT; ++c) mx = fmaxf(mx, fabsf(xf[c]));
#pragma unroll
        for (int off = 32; off; off >>= 1)
            mx = fmaxf(mx, __shfl_down(mx, off));
        if (lane == 0) redX[wid] = mx;
        lds_barrier();   // #1 — all waves' stages of row r complete + redX visible

        float inorm = redX[0];
#pragma unroll
        for (int i = 1; i < 8; ++i) inorm = fmaxf(inorm, redX[i]);
        inorm = (inorm <= 1e-9f) ? 1.f : inorm;
        const double inv_d = 1.0 / (double)inorm;   // correctly-rounded f32 recip seed
        const float  y     = (float)inv_d;

        // halos (cross-wave staged data — safe after barrier #1)
        const float4 hv1 = xs[buf][hiL];
        const float4 hv2 = xs[buf][hiR];

        float Q[EPT + 4];
#pragma unroll
        for (int c = 0; c < EPT; ++c) QF(Q[c + 2], fabsf(xf[c]));
        QF(Q[0],  fabsf(hv1.z)); QF(Q[1],  fabsf(hv1.w));
        QF(Q[18], fabsf(hv2.x)); QF(Q[19], fabsf(hv2.y));
        if (t == 0)      { Q[0]  = 0.f; Q[1]  = 0.f; }   // conv 'SAME' zero pad
        if (t == BT - 1) { Q[18] = 0.f; Q[19] = 0.f; }

        // ---- conv + D/T accumulate (4 rotating f32 chains, R4-identical) ----
        float Dv[4] = {0.f,0.f,0.f,0.f}, Tv[4] = {0.f,0.f,0.f,0.f};
        double cD = 0.0, cT = 0.0;
#pragma unroll
        for (int c = 0; c < EPT; ++c) {
            const float s1 = Q[c + 1] + Q[c + 3];
            const float s2 = Q[c]     + Q[c + 4];
            float cv = fmaf(0.01f, s1, Q[c + 2]);
            cv = fmaf(0.0025f, s2, cv);
            const float sel = (xf[c] > 0.f) ? wf[c] : -wf[c];
            Dv[c & 3] = fmaf(cv, sel,        Dv[c & 3]);
            Tv[c & 3] = fmaf(cv, fabsf(sel), Tv[c & 3]);
        }
        if (t == 0) {
#pragma unroll
            for (int c = 0; c < 2; ++c) {
                const float s1 = Q[c + 1] + Q[c + 3];
                const float s2 = Q[c]     + Q[c + 4];
                float cv = fmaf(0.01f, s1, Q[c + 2]);
                cv = fmaf(0.0025f, s2, cv);
                const float sel = (xf[c] > 0.f) ? wf[c] : -wf[c];
                const double de = (c == 0) ? DE0 : DE1;
                cD += de * (double)(cv * sel);
                cT += de * (double)(cv * fabsf(sel));
            }
        }
        if (t == BT - 1) {
#pragma unroll
            for (int c = EPT - 2; c < EPT; ++c) {
                const float s1 = Q[c + 1] + Q[c + 3];
                const float s2 = Q[c]     + Q[c + 4];
                float cv = fmaf(0.01f, s1, Q[c + 2]);
                cv = fmaf(0.0025f, s2, cv);
                const float sel = (xf[c] > 0.f) ? wf[c] : -wf[c];
                const double de = (c == EPT - 1) ? DE0 : DE1;
                cD += de * (double)(cv * sel);
                cT += de * (double)(cv * fabsf(sel));
            }
        }

        double accD = ((double)Dv[0] + (double)Dv[1]) + ((double)Dv[2] + (double)Dv[3]);
        float  accT = (Tv[0] + Tv[1]) + (Tv[2] + Tv[3]);
        float  mww  = mw;
#pragma unroll
        for (int off = 32; off; off >>= 1) {
            accD += __shfl_down(accD, off);
            accT += __shfl_down(accT, off);
            mww   = fmaxf(mww, __shfl_down(mww, off));
        }
        if (lane == 0)   { redD[wid] = accD; redT[wid] = accT; redW[wid] = mww; }
        if (t == 0)      { corrd[0] = cD; corrd[1] = cT; }
        if (t == BT - 1) { corrd[2] = cD; corrd[3] = cT; }
        lds_barrier();   // #2

        if (t == 0) {
            double D = 0.0, T = 0.0;
            float wn = redW[0];
#pragma unroll
            for (int i = 0; i < 8; ++i) {
                D += redD[i]; T += (double)redT[i];
                wn = fmaxf(wn, redW[i]);
            }
            if (r == 0) wnorm = (wn <= 1e-9f) ? 1.f : wn;

            D = D * E_MID + (corrd[0] + corrd[2]);
            T = T * E_MID + (corrd[1] + corrd[3]);

            const double Kd = (10.0 / 255.0) * (YB_LOSS_D * MZM_LOSS_D) / (double)wnorm;
            const double ps = (T + D) * 0.5 * Kd * MRR_LOSS_D;
            const double ns = (T - D) * 0.5 * Kd * MRR_LOSS_D;

            const float thermal_f = 3.3135576e-12f;   // f32(4*kB*T*Hz/R)
            const float shot_f    = 3.204353268e-9f;  // f32(2*qE*Hz)
            const int   row_      = r0 + r;

            double tp_ = ps + 1e-12 + (double)(ntp[row_] * thermal_f);
            tp_ *= (double)(1.0f + nsp[row_] * shot_f);   // == *1.0 in f32, faithful
            double tn_ = ns + 1e-12 + (double)(ntn[row_] * thermal_f);
            tn_ *= (double)(1.0f + nsn[row_] * shot_f);

            const double cur = tp_ - tn_;
            double v = fabs(cur * 100.0);
            v = fmin(v, 1.0);
            const double va  = rint(v * 255.0) * (1.0 / 255.0);
            const double sgn = (cur >= 0.0) ? 1.0 : -1.0;
            const double scale = (double)wnorm /
                (10.0 * 100.0 * MRR_LOSS_D * YB_LOSS_D * MZM_LOSS_D);
            ov[r] = (float)(va * sgn * scale * (double)inorm);
        }
    }

    // ---- epilogue: thread 0 writes the block's 8 outputs ----
    if (t == 0) {
        float4 o0 = make_float4(ov[0], ov[1], ov[2], ov[3]);
        float4 o1 = make_float4(ov[4], ov[5], ov[6], ov[7]);
        *(float4*)(out + r0)     = o0;
        *(float4*)(out + r0 + 4) = o1;
    }
#undef STAGE
}

extern "C" void kernel_launch(void* const* d_in, const int* in_sizes, int n_in,
                              void* d_out, int out_size, void* d_ws, size_t ws_size,
                              hipStream_t stream) {
    const float* x   = (const float*)d_in[0];
    const float* w   = (const float*)d_in[1];
    const float* ntp = (const float*)d_in[2];
    const float* nsp = (const float*)d_in[3];
    const float* ntn = (const float*)d_in[4];
    const float* nsn = (const float*)d_in[5];
    float* out = (float*)d_out;
    const int nblocks = out_size / ROWS;   // B=4096 -> 512 blocks, 2/CU, persistent
    odp_main<<<dim3(nblocks), dim3(BT), 0, stream>>>(x, w, ntp, nsp, ntn, nsn, out);
}

// Round 13
// 31.341 us; speedup vs baseline: 1.1688x; 1.1688x over previous
//
#include <hip/hip_runtime.h>
#include <math.h>

#define NCOL 8192
#define BT   512
#define EPT  16
#define ROWS 2

// exact double constants
#define MZM_LOSS_D 0.8912509381337456   // 10^-0.05
#define YB_LOSS_D  0.9332543007969910   // 10^-0.03
#define MRR_LOSS_D 0.8912509381337456   // 10^-0.05

static __device__ __forceinline__ void lds_barrier() {
    // drain LDS/SMEM only; outstanding global loads ride through the barrier
    asm volatile("s_waitcnt lgkmcnt(0)" ::: "memory");
    __builtin_amdgcn_s_barrier();
}

// Markstein: dst = rint(f32div(a, INORM) * 255), exact IEEE f32 division
#define QF(dst, a_, INORM, Y) do {                         \
    const float a__  = (a_);                               \
    const float q0__ = a__ * (Y);                          \
    const float r__  = fmaf(-(INORM), q0__, a__);          \
    (dst) = rintf(fmaf(r__, (Y), q0__) * 255.f);           \
} while (0)

// quant + conv + masked D/T accumulate for one 16-elem row slice (R4-identical)
#define ROW_COMPUTE(XF, HXL, HXR, INORM, Y, ACCD, ACCT, CDV, CTV) do {        \
    float Q[EPT + 4];                                                         \
    _Pragma("unroll")                                                         \
    for (int c = 0; c < EPT; ++c) QF(Q[c + 2], fabsf(XF[c]), INORM, Y);       \
    QF(Q[0],  fabsf(HXL.x), INORM, Y);                                        \
    QF(Q[1],  fabsf(HXL.y), INORM, Y);                                        \
    QF(Q[18], fabsf(HXR.x), INORM, Y);                                        \
    QF(Q[19], fabsf(HXR.y), INORM, Y);                                        \
    if (t == 0)      { Q[0]  = 0.f; Q[1]  = 0.f; }                            \
    if (t == BT - 1) { Q[18] = 0.f; Q[19] = 0.f; }                            \
    float Dv[4] = {0.f,0.f,0.f,0.f}, Tv[4] = {0.f,0.f,0.f,0.f};               \
    _Pragma("unroll")                                                         \
    for (int c = 0; c < EPT; ++c) {                                           \
        const float s1 = Q[c + 1] + Q[c + 3];                                 \
        const float s2 = Q[c]     + Q[c + 4];                                 \
        float cv = fmaf(0.01f, s1, Q[c + 2]);                                 \
        cv = fmaf(0.0025f, s2, cv);                                           \
        const float sel = (XF[c] > 0.f) ? wf[c] : -wf[c];                     \
        Dv[c & 3] = fmaf(cv, sel,        Dv[c & 3]);                          \
        Tv[c & 3] = fmaf(cv, fabsf(sel), Tv[c & 3]);                          \
        if ((t == 0 && c < 2) || (t == BT - 1 && c >= EPT - 2)) {             \
            const double de = (c == 0 || c == EPT - 1) ? DE0 : DE1;           \
            CDV += de * (double)(cv * sel);                                   \
            CTV += de * (double)(cv * fabsf(sel));                            \
        }                                                                     \
    }                                                                         \
    ACCD = ((double)Dv[0] + (double)Dv[1]) + ((double)Dv[2] + (double)Dv[3]); \
    ACCT = (Tv[0] + Tv[1]) + (Tv[2] + Tv[3]);                                 \
} while (0)

// thread-0 scalar tail for one row -> output value
#define ROW_TAIL(REDD, REDT, CORR, INORM, NTP, NSP, NTN, NSN, OV) do {        \
    double D = 0.0, T = 0.0;                                                  \
    _Pragma("unroll")                                                         \
    for (int i = 0; i < 8; ++i) { D += REDD[i]; T += (double)REDT[i]; }       \
    D = D * E_MID + (CORR[0] + CORR[2]);                                      \
    T = T * E_MID + (CORR[1] + CORR[3]);                                      \
    const double Kd = (10.0 / 255.0) * (YB_LOSS_D * MZM_LOSS_D) / (double)wnorm;\
    const double ps = (T + D) * 0.5 * Kd * MRR_LOSS_D;                        \
    const double ns = (T - D) * 0.5 * Kd * MRR_LOSS_D;                        \
    const float thermal_f = 3.3135576e-12f;                                   \
    const float shot_f    = 3.204353268e-9f;                                  \
    double tp_ = ps + 1e-12 + (double)((NTP) * thermal_f);                    \
    tp_ *= (double)(1.0f + (NSP) * shot_f);                                   \
    double tn_ = ns + 1e-12 + (double)((NTN) * thermal_f);                    \
    tn_ *= (double)(1.0f + (NSN) * shot_f);                                   \
    const double cur = tp_ - tn_;                                             \
    double v = fabs(cur * 100.0);                                             \
    v = fmin(v, 1.0);                                                         \
    const double va  = rint(v * 255.0) * (1.0 / 255.0);                       \
    const double sgn = (cur >= 0.0) ? 1.0 : -1.0;                             \
    const double scale = (double)wnorm /                                      \
        (10.0 * 100.0 * MRR_LOSS_D * YB_LOSS_D * MZM_LOSS_D);                 \
    OV = (float)(va * sgn * scale * (double)(INORM));                         \
} while (0)

__global__ __launch_bounds__(BT, 4)
void odp_main(const float* __restrict__ x, const float* __restrict__ w,
              const float* __restrict__ ntp, const float* __restrict__ nsp,
              const float* __restrict__ ntn, const float* __restrict__ nsn,
              float* __restrict__ out)
{
    __shared__ float  redX0[8], redX1[8], redW[8];
    __shared__ float  redT0[8], redT1[8];
    __shared__ double redD0[8], redD1[8];
    __shared__ double corr0[4], corr1[4];

    const int t    = threadIdx.x;
    const int lane = t & 63;
    const int wid  = t >> 6;
    const int r0   = blockIdx.x * ROWS;

    const double DE0 = -((double)0.01f + (double)0.0025f);  // elems 0, N-1
    const double DE1 = -((double)0.0025f);                  // elems 1, N-2
    const double E_MID = 1.0 + 2.0 * (double)0.01f + 2.0 * (double)0.0025f;

    // uniform scalar loads (s_load path), both rows' noise
    const float vntp0 = ntp[r0],     vnsp0 = nsp[r0];
    const float vntn0 = ntn[r0],     vnsn0 = nsn[r0];
    const float vntp1 = ntp[r0 + 1], vnsp1 = nsp[r0 + 1];
    const float vntn1 = ntn[r0 + 1], vnsn1 = nsn[r0 + 1];

    const float*  __restrict__ xrow0 = x + (size_t)r0 * NCOL;
    const float*  __restrict__ xrow1 = xrow0 + NCOL;
    const float4* __restrict__ xr40  = (const float4*)xrow0;
    const float4* __restrict__ xr41  = (const float4*)xrow1;
    const float4* __restrict__ w4    = (const float4*)w;

    // ---- issue ALL loads up front: row0 (5), w (4), row1 (5) = 64 KB/block ----
    float xf0[EPT], xf1[EPT], wf[EPT];
#pragma unroll
    for (int j = 0; j < 4; ++j) {
        const float4 v = xr40[t * 4 + j];
        xf0[4*j+0]=v.x; xf0[4*j+1]=v.y; xf0[4*j+2]=v.z; xf0[4*j+3]=v.w;
    }
    const float2 hxL0 = *(const float2*)(xrow0 + ((t > 0)      ? t*EPT - 2   : 0));
    const float2 hxR0 = *(const float2*)(xrow0 + ((t < BT - 1) ? t*EPT + EPT : NCOL - 2));
#pragma unroll
    for (int j = 0; j < 4; ++j) {
        const float4 v = w4[t * 4 + j];
        wf[4*j+0]=v.x; wf[4*j+1]=v.y; wf[4*j+2]=v.z; wf[4*j+3]=v.w;
    }
#pragma unroll
    for (int j = 0; j < 4; ++j) {
        const float4 v = xr41[t * 4 + j];
        xf1[4*j+0]=v.x; xf1[4*j+1]=v.y; xf1[4*j+2]=v.z; xf1[4*j+3]=v.w;
    }
    const float2 hxL1 = *(const float2*)(xrow1 + ((t > 0)      ? t*EPT - 2   : 0));
    const float2 hxR1 = *(const float2*)(xrow1 + ((t < BT - 1) ? t*EPT + EPT : NCOL - 2));

    // ---- row-0 max reduce (waits only on row-0 regs) ----
    float mx0 = 0.f;
#pragma unroll
    for (int c = 0; c < EPT; ++c) mx0 = fmaxf(mx0, fabsf(xf0[c]));
#pragma unroll
    for (int off = 32; off; off >>= 1)
        mx0 = fmaxf(mx0, __shfl_down(mx0, off));
    if (lane == 0) redX0[wid] = mx0;
    lds_barrier();   // B1 (w, x1 still in flight)

    float inorm0 = redX0[0];
#pragma unroll
    for (int i = 1; i < 8; ++i) inorm0 = fmaxf(inorm0, redX0[i]);
    inorm0 = (inorm0 <= 1e-9f) ? 1.f : inorm0;
    const double invd0 = 1.0 / (double)inorm0;
    const float  y0    = (float)invd0;

    // per-thread max|w| (w regs now needed anyway)
    float mw = 0.f;
#pragma unroll
    for (int c = 0; c < EPT; ++c) mw = fmaxf(mw, fabsf(wf[c]));

    // ---- row 0 compute ----
    double accD0, cD0 = 0.0, cT0 = 0.0;
    float  accT0;
    ROW_COMPUTE(xf0, hxL0, hxR0, inorm0, y0, accD0, accT0, cD0, cT0);

    // ---- row-1 max reduce (x1 landed during row-0 compute) ----
    float mx1 = 0.f;
#pragma unroll
    for (int c = 0; c < EPT; ++c) mx1 = fmaxf(mx1, fabsf(xf1[c]));
#pragma unroll
    for (int off = 32; off; off >>= 1)
        mx1 = fmaxf(mx1, __shfl_down(mx1, off));
    if (lane == 0) redX1[wid] = mx1;

    // ---- row-0 D/T/mw reduce ----
#pragma unroll
    for (int off = 32; off; off >>= 1) {
        accD0 += __shfl_down(accD0, off);
        accT0 += __shfl_down(accT0, off);
        mw     = fmaxf(mw, __shfl_down(mw, off));
    }
    if (lane == 0)   { redD0[wid] = accD0; redT0[wid] = accT0; redW[wid] = mw; }
    if (t == 0)      { corr0[0] = cD0; corr0[1] = cT0; }
    if (t == BT - 1) { corr0[2] = cD0; corr0[3] = cT0; }
    lds_barrier();   // B2

    // wnorm (all threads; cheap) — needed by tails in thread 0
    float wnorm = redW[0];
#pragma unroll
    for (int i = 1; i < 8; ++i) wnorm = fmaxf(wnorm, redW[i]);
    wnorm = (wnorm <= 1e-9f) ? 1.f : wnorm;

    float ov0 = 0.f, ov1 = 0.f;
    if (t == 0) ROW_TAIL(redD0, redT0, corr0, inorm0, vntp0, vnsp0, vntn0, vnsn0, ov0);

    // ---- row 1 compute ----
    float inorm1 = redX1[0];
#pragma unroll
    for (int i = 1; i < 8; ++i) inorm1 = fmaxf(inorm1, redX1[i]);
    inorm1 = (inorm1 <= 1e-9f) ? 1.f : inorm1;
    const double invd1 = 1.0 / (double)inorm1;
    const float  y1    = (float)invd1;

    double accD1, cD1 = 0.0, cT1 = 0.0;
    float  accT1;
    ROW_COMPUTE(xf1, hxL1, hxR1, inorm1, y1, accD1, accT1, cD1, cT1);

#pragma unroll
    for (int off = 32; off; off >>= 1) {
        accD1 += __shfl_down(accD1, off);
        accT1 += __shfl_down(accT1, off);
    }
    if (lane == 0)   { redD1[wid] = accD1; redT1[wid] = accT1; }
    if (t == 0)      { corr1[0] = cD1; corr1[1] = cT1; }
    if (t == BT - 1) { corr1[2] = cD1; corr1[3] = cT1; }
    lds_barrier();   // B3

    if (t == 0) {
        ROW_TAIL(redD1, redT1, corr1, inorm1, vntp1, vnsp1, vntn1, vnsn1, ov1);
        *(float2*)(out + r0) = make_float2(ov0, ov1);
    }
}

extern "C" void kernel_launch(void* const* d_in, const int* in_sizes, int n_in,
                              void* d_out, int out_size, void* d_ws, size_t ws_size,
                              hipStream_t stream) {
    const float* x   = (const float*)d_in[0];
    const float* w   = (const float*)d_in[1];
    const float* ntp = (const float*)d_in[2];
    const float* nsp = (const float*)d_in[3];
    const float* ntn = (const float*)d_in[4];
    const float* nsn = (const float*)d_in[5];
    float* out = (float*)d_out;
    const int nblocks = out_size / ROWS;   // 4096 -> 2048 blocks
    odp_main<<<dim3(nblocks), dim3(BT), 0, stream>>>(x, w, ntp, nsp, ntn, nsn, out);
}